// Round 17
// baseline (325.250 us; speedup 1.0000x reference)
//
#include <hip/hip_runtime.h>
#include <hip/hip_bf16.h>
#include <math.h>

#define EPSF 1e-7f
#define MAXT 0.99999f   // 1 - 1e-5

typedef __attribute__((ext_vector_type(8))) short short8v;   // 8 x bf16 (4 VGPR)
typedef __attribute__((ext_vector_type(4))) float f32x4;     // MFMA C/D frag

constexpr int Bb = 2048;
constexpr int Ss = 768;
constexpr int Dd = 128;
constexpr int Nn = 100000;
constexpr int Kk = 5;
constexpr int HALF = Bb * Dd;        // 262144
constexpr int NT = 128;              // nodes per tile
constexpr int TILE_BYTES = NT * Dd * 2;  // 32768
constexpr int SUP_BYTES = 2 * TILE_BYTES;  // 64KB super-tile (2 tiles)
constexpr float SBIAS = 16.0f;       // score-positivity bias (|2 s dot| < 12.5)

// fast path: transposed MFMA (A=emb', B=z), 8 chunks of 12500, 98 tiles/chunk
constexpr int NCH8 = 8;
constexpr int CH8 = Nn / NCH8;       // 12500
constexpr int TIL8 = 98;             // tiles/chunk; 49 super-tiles exactly
constexpr int NSUP = TIL8 / 2;       // 49
constexpr int PAD8 = TIL8 * NT;      // 12544 padded slots per chunk (fits 14 bits)
constexpr int RQ = 64;               // query rows per block

// legacy path (round-3, verified): 16 chunks of 6250, in-loop cvt staging
constexpr int NCH16 = 16;
constexpr int CH16 = Nn / NCH16;     // 6250
constexpr int TIL16 = (CH16 + NT - 1) / NT;  // 49
constexpr int RT = 128;

static __device__ __forceinline__ ushort f2bf(float x) {
  __hip_bfloat16 h = __float2bfloat16(x);
  return *reinterpret_cast<ushort*>(&h);
}

static __device__ __forceinline__ float med3f(float a, float b, float c) {
  float r;
  asm("v_med3_f32 %0, %1, %2, %3" : "=v"(r) : "v"(a), "v"(b), "v"(c));
  return r;
}

// Branchless insert of v into ascending sorted k[0..4], keep 5 smallest.
// Keys are positive finite floats whose uint order == float order.
static __device__ __forceinline__ void ins5f(float* k, float v) {
  const float n0 = fminf(k[0], v);
  const float n1 = med3f(k[0], k[1], v);
  const float n2 = med3f(k[1], k[2], v);
  const float n3 = med3f(k[2], k[3], v);
  const float n4 = med3f(k[3], k[4], v);
  k[0] = n0; k[1] = n1; k[2] = n2; k[3] = n3; k[4] = n4;
}

// Insert into ascending-sorted top-5 (value,index) — legacy path only.
#define INS5(TV, TI, V, ID) do { \
  const float _v = (V); const int _id = (ID); \
  if (_v < TV[4]) { \
    TV[4] = _v; TI[4] = _id; \
    if (TV[4] < TV[3]) { float _t=TV[3];TV[3]=TV[4];TV[4]=_t;int _u=TI[3];TI[3]=TI[4];TI[4]=_u; } \
    if (TV[3] < TV[2]) { float _t=TV[2];TV[2]=TV[3];TV[3]=_t;int _u=TI[2];TI[2]=TI[3];TI[3]=_u; } \
    if (TV[2] < TV[1]) { float _t=TV[1];TV[1]=TV[2];TV[2]=_t;int _u=TI[1];TI[1]=TI[2];TI[2]=_u; } \
    if (TV[1] < TV[0]) { float _t=TV[0];TV[0]=TV[1];TV[1]=_t;int _u=TI[0];TI[0]=TI[1];TI[1]=_u; } \
  } } while(0)

// Lexicographic (value, index) insert for merging unordered candidate streams.
#define LXLT(V,I,V2,I2) ((V) < (V2) || ((V) == (V2) && (I) < (I2)))
#define INS5L(TV, TI, V, ID) do { \
  const float _v = (V); const int _id = (ID); \
  if (LXLT(_v,_id,TV[4],TI[4])) { \
    TV[4]=_v; TI[4]=_id; \
    if (LXLT(TV[4],TI[4],TV[3],TI[3])) { float _t=TV[3];TV[3]=TV[4];TV[4]=_t;int _u=TI[3];TI[3]=TI[4];TI[4]=_u; } \
    if (LXLT(TV[3],TI[3],TV[2],TI[2])) { float _t=TV[2];TV[2]=TV[3];TV[3]=_t;int _u=TI[2];TI[2]=TI[3];TI[3]=_u; } \
    if (LXLT(TV[2],TI[2],TV[1],TI[1])) { float _t=TV[1];TV[1]=TV[2];TV[2]=_t;int _u=TI[1];TI[1]=TI[2];TI[2]=_u; } \
    if (LXLT(TV[1],TI[1],TV[0],TI[0])) { float _t=TV[0];TV[0]=TV[1];TV[1]=_t;int _u=TI[0];TI[0]=TI[1];TI[1]=_u; } \
  } } while(0)

// ---------------------------------------------------------------------------
// Shared proj body: 8 rows, 256 threads split-K.
static __device__ __forceinline__ void proj_body(
    const float* __restrict__ zseq, const float* __restrict__ W,
    const float* __restrict__ bias, float* __restrict__ outH,
    ushort* __restrict__ ztb, int blk,
    float (*zrow)[768], float (*zp)[128], float (*php)[128], float* rno)
{
  const int tid = threadIdx.x;
  const int d = tid & 127, h = tid >> 7;
  const int r0 = blk * 8;

  {
    const float4* src = reinterpret_cast<const float4*>(zseq + (size_t)r0 * Ss);
    float4* dst = reinterpret_cast<float4*>(&zrow[0][0]);
    #pragma unroll
    for (int i = 0; i < 6; ++i) dst[i * 256 + tid] = src[i * 256 + tid];
  }
  __syncthreads();

  float acc[8];
  #pragma unroll
  for (int r = 0; r < 8; ++r) acc[r] = 0.f;
  const float4* w4 = reinterpret_cast<const float4*>(W + (size_t)d * Ss) + h * 96;
  for (int j = 0; j < 96; ++j) {
    const float4 w = w4[j];
    const int kb = h * 384 + j * 4;
    #pragma unroll
    for (int r = 0; r < 8; ++r) {
      const float4 z = *reinterpret_cast<const float4*>(&zrow[r][kb]);
      acc[r] = fmaf(z.x, w.x, acc[r]);
      acc[r] = fmaf(z.y, w.y, acc[r]);
      acc[r] = fmaf(z.z, w.z, acc[r]);
      acc[r] = fmaf(z.w, w.w, acc[r]);
    }
  }
  #pragma unroll
  for (int r = 0; r < 8; ++r) {
    if (h == 0) zp[r][d] = acc[r]; else php[r][d] = acc[r];
  }
  __syncthreads();
  if (tid < 128) {
    const float bv = bias[d];
    #pragma unroll
    for (int r = 0; r < 8; ++r) zp[r][d] = zp[r][d] + php[r][d] + bv;
  }
  __syncthreads();

  const int wv = tid >> 6, ln = tid & 63;
  if (tid < 128) {
    #pragma unroll
    for (int rr = 0; rr < 4; ++rr) {
      const int r = wv * 4 + rr;
      float v = zp[r][ln] * zp[r][ln] + zp[r][ln + 64] * zp[r][ln + 64];
      #pragma unroll
      for (int off = 32; off > 0; off >>= 1) v += __shfl_xor(v, off);
      if (ln == 0) rno[r] = v;
    }
  }
  __syncthreads();
  if (tid < 128) {
    #pragma unroll
    for (int r = 0; r < 8; ++r) {
      const float n = fmaxf(sqrtf(rno[r]), EPSF);
      const float zh = tanhf(n) * zp[r][d] / n;
      outH[(size_t)(r0 + r) * Dd + d] = zh;   // z_hyp output (f32)
      zp[r][d] = zh;
    }
  }
  __syncthreads();
  if (tid < 128) {
    #pragma unroll
    for (int rr = 0; rr < 4; ++rr) {
      const int r = wv * 4 + rr;
      float v = zp[r][ln] * zp[r][ln] + zp[r][ln + 64] * zp[r][ln + 64];
      #pragma unroll
      for (int off = 32; off > 0; off >>= 1) v += __shfl_xor(v, off);
      if (ln == 0) rno[r] = v;
    }
  }
  __syncthreads();
  if (tid < 128) {
    #pragma unroll
    for (int r = 0; r < 8; ++r) {
      const float m = fmaxf(sqrtf(rno[r]), EPSF);
      const float a = atanhf(fminf(m, MAXT));
      ztb[(size_t)(r0 + r) * Dd + d] = f2bf(a * zp[r][d] / m);
    }
  }
}

// Legacy-path standalone proj.
__global__ __launch_bounds__(256) void k_proj(
    const float* __restrict__ zseq, const float* __restrict__ W,
    const float* __restrict__ bias, float* __restrict__ outH,
    ushort* __restrict__ ztb)
{
  __shared__ __align__(16) float zrow[8][768];
  __shared__ float zp[8][128];
  __shared__ float php[8][128];
  __shared__ float rno[8];
  proj_body(zseq, W, bias, outH, ztb, blockIdx.x, zrow, zp, php, rno);
}

// ---------------------------------------------------------------------------
// FAST PATH fused prep: blocks [0,256) run proj; blocks [256,...) run pack.
// Pack: 2 nodes per wave (per-lane float4, 32-lane-half reduce). emb' =
// bf16(-2*s_n*emb_n), XOR-SWIZZLED tiled image (byte ^= (node&7)<<4).
// cpad[slot] = c_n + SBIAS or +INF for pad slots.
__global__ __launch_bounds__(256) void k_prep(
    const float* __restrict__ zseq, const float* __restrict__ W,
    const float* __restrict__ bias, float* __restrict__ outH,
    ushort* __restrict__ ztb, const float* __restrict__ emb,
    ushort* __restrict__ embsw, float* __restrict__ cpad)
{
  __shared__ __align__(16) float zrow[8][768];
  __shared__ float zp[8][128];
  __shared__ float php[8][128];
  __shared__ float rno[8];

  if (blockIdx.x < Bb / 8) {
    proj_body(zseq, W, bias, outH, ztb, blockIdx.x, zrow, zp, php, rno);
    return;
  }

  // ---- pack part: wave handles 2 nodes (32-lane half each, float4/lane)
  const int wv = threadIdx.x >> 6, ln = threadIdx.x & 63;
  const int half = ln >> 5, l5 = ln & 31;
  const int p = (blockIdx.x - Bb / 8) * 8 + wv * 2 + half;   // padded slot
  const int chunk = p / PAD8;
  const int local = p - chunk * PAD8;
  const bool real = local < CH8;
  const int node = chunk * CH8 + local;
  float4 v = make_float4(0.f, 0.f, 0.f, 0.f);
  if (real) v = *reinterpret_cast<const float4*>(emb + (size_t)node * Dd + l5 * 4);
  float t = v.x * v.x + v.y * v.y + v.z * v.z + v.w * v.w;
  #pragma unroll
  for (int off = 16; off > 0; off >>= 1) t += __shfl_xor(t, off);  // within half

  const float E = fmaxf(sqrtf(t), EPSF);
  const float a = atanhf(fminf(E, MAXT));
  const float s = a / E;
  const float m2s = -2.f * s;

  const int tt = local >> 7, nd = local & 127;
  ushort4 w;
  w.x = f2bf(m2s * v.x); w.y = f2bf(m2s * v.y);
  w.z = f2bf(m2s * v.z); w.w = f2bf(m2s * v.w);
  char* dst = reinterpret_cast<char*>(embsw)
            + ((size_t)((chunk * TIL8 + tt) * NT + nd) << 8)
            + ((l5 * 8) ^ ((nd & 7) << 4));
  *reinterpret_cast<ushort4*>(dst) = w;

  if (l5 == 0) cpad[p] = real ? (s * s * t + SBIAS) : 3.0e38f;
}

// ---------------------------------------------------------------------------
// FAST PATH topk: R16 super-tile structure with DEDUPLICATED LDS reads:
// wave w (0..15) owns node slice w*16 of the 256-node super (tile w>>3) and
// computes ALL 64 q-rows for it (zfr[4][4], 4 MFMA chains). Per super per
// wave: 4 ds_read_b128 (was 8), 16 MFMA, 1 cv register load -> uniform
// vmcnt(5). LDS read bytes/CU/super = exactly the 64KB super (was 2x).
__global__ __launch_bounds__(1024, 4) void k_topk8(
    const ushort* __restrict__ ztb, const ushort* __restrict__ embsw,
    const float* __restrict__ cpad, float* __restrict__ candV,
    int* __restrict__ candI)
{
  __shared__ __align__(16) ushort Bsm[2][2][NT * Dd];  // 2 super-bufs x 2 tiles

  const int tid = threadIdx.x;
  const int ln = tid & 63;
  const int w = tid >> 6;           // 0..15 : node slice (16 of 256)
  const int ln15 = ln & 15;
  const int g = ln >> 4;            // 0..3
  const int chunk = blockIdx.x & 7;            // XCD-pinned chunk (proven R8)
  const int rowBase = (blockIdx.x >> 3) * RQ;
  const char* embc = reinterpret_cast<const char*>(embsw)
                   + (size_t)chunk * (TIL8 * TILE_BYTES);
  const float* cch = cpad + (size_t)chunk * PAD8;
  const int tu = w >> 3;            // which tile of the super this wave reads

  // B operand: z fragments for ALL 64 q-rows (4 groups of 16), reused always.
  short8v zfr[4][4];
  #pragma unroll
  for (int f = 0; f < 4; ++f)
    #pragma unroll
    for (int ks = 0; ks < 4; ++ks)
      zfr[f][ks] = *reinterpret_cast<const short8v*>(
          ztb + (size_t)(rowBase + 16 * f + ln15) * Dd + 32 * ks + 8 * g);

  // A operand LDS byte offsets (SWIZZLED): node = (w&7)*16+ln15 within tile tu
  int rdoff[4];
  #pragma unroll
  for (int ks = 0; ks < 4; ++ks)
    rdoff[ks] = ((w & 7) * 16 + ln15) * 256 + ((ks * 64 + g * 16) ^ ((ln15 & 7) << 4));
  const unsigned lanebase = (unsigned)(w * 16 + 4 * g);   // node within super

  float tv0[5], tv1[5], tv2[5], tv3[5];
  const float KINIT = __uint_as_float(0x7F7FFFFFu);   // max finite float
  #pragma unroll
  for (int q = 0; q < 5; ++q) { tv0[q] = KINIT; tv1[q] = KINIT; tv2[q] = KINIT; tv3[q] = KINIT; }

  // rolling staging pointers (advance one SUPER-tile per STAGE).
  const char* srcP = embc + tid * 16;
  unsigned long long cvP =
      (unsigned long long)(cch + tu * NT + (w & 7) * 16 + 4 * g);

  f32x4 cvA, cvB;   // per-super biased c for this lane's 4 nodes (dbuf)

#define STAGE(BB, CV) do { \
    char* lb = reinterpret_cast<char*>(&Bsm[BB][0][0]) + tid * 16; \
    __builtin_amdgcn_global_load_lds( \
        (const __attribute__((address_space(1))) unsigned int*)(srcP), \
        (__attribute__((address_space(3))) unsigned int*)(lb), 16, 0, 0); \
    __builtin_amdgcn_global_load_lds( \
        (const __attribute__((address_space(1))) unsigned int*)(srcP + 16384), \
        (__attribute__((address_space(3))) unsigned int*)(lb + 16384), 16, 0, 0); \
    __builtin_amdgcn_global_load_lds( \
        (const __attribute__((address_space(1))) unsigned int*)(srcP + 32768), \
        (__attribute__((address_space(3))) unsigned int*)(lb + 32768), 16, 0, 0); \
    __builtin_amdgcn_global_load_lds( \
        (const __attribute__((address_space(1))) unsigned int*)(srcP + 49152), \
        (__attribute__((address_space(3))) unsigned int*)(lb + 49152), 16, 0, 0); \
    asm volatile("global_load_dwordx4 %0, %1, off" \
        : "=&v"(CV) : "v"(cvP)); \
    srcP += SUP_BYTES; \
    cvP += (unsigned long long)(2 * NT * 4); } while (0)

#define PROCSUP(BB, CV, ST, WN) do { \
    asm volatile("s_waitcnt vmcnt(" #WN ")" ::: "memory"); \
    __builtin_amdgcn_sched_barrier(0); \
    __builtin_amdgcn_s_barrier(); \
    const char* bbase = reinterpret_cast<const char*>(&Bsm[BB][tu][0]); \
    const short8v ae0 = *reinterpret_cast<const short8v*>(bbase + rdoff[0]); \
    const short8v ae1 = *reinterpret_cast<const short8v*>(bbase + rdoff[1]); \
    const short8v ae2 = *reinterpret_cast<const short8v*>(bbase + rdoff[2]); \
    const short8v ae3 = *reinterpret_cast<const short8v*>(bbase + rdoff[3]); \
    __builtin_amdgcn_s_setprio(1); \
    f32x4 a0 = __builtin_amdgcn_mfma_f32_16x16x32_bf16(ae0, zfr[0][0], CV, 0, 0, 0); \
    f32x4 a1 = __builtin_amdgcn_mfma_f32_16x16x32_bf16(ae0, zfr[1][0], CV, 0, 0, 0); \
    f32x4 a2 = __builtin_amdgcn_mfma_f32_16x16x32_bf16(ae0, zfr[2][0], CV, 0, 0, 0); \
    f32x4 a3 = __builtin_amdgcn_mfma_f32_16x16x32_bf16(ae0, zfr[3][0], CV, 0, 0, 0); \
    a0 = __builtin_amdgcn_mfma_f32_16x16x32_bf16(ae1, zfr[0][1], a0, 0, 0, 0); \
    a1 = __builtin_amdgcn_mfma_f32_16x16x32_bf16(ae1, zfr[1][1], a1, 0, 0, 0); \
    a2 = __builtin_amdgcn_mfma_f32_16x16x32_bf16(ae1, zfr[2][1], a2, 0, 0, 0); \
    a3 = __builtin_amdgcn_mfma_f32_16x16x32_bf16(ae1, zfr[3][1], a3, 0, 0, 0); \
    a0 = __builtin_amdgcn_mfma_f32_16x16x32_bf16(ae2, zfr[0][2], a0, 0, 0, 0); \
    a1 = __builtin_amdgcn_mfma_f32_16x16x32_bf16(ae2, zfr[1][2], a1, 0, 0, 0); \
    a2 = __builtin_amdgcn_mfma_f32_16x16x32_bf16(ae2, zfr[2][2], a2, 0, 0, 0); \
    a3 = __builtin_amdgcn_mfma_f32_16x16x32_bf16(ae2, zfr[3][2], a3, 0, 0, 0); \
    a0 = __builtin_amdgcn_mfma_f32_16x16x32_bf16(ae3, zfr[0][3], a0, 0, 0, 0); \
    a1 = __builtin_amdgcn_mfma_f32_16x16x32_bf16(ae3, zfr[1][3], a1, 0, 0, 0); \
    a2 = __builtin_amdgcn_mfma_f32_16x16x32_bf16(ae3, zfr[2][3], a2, 0, 0, 0); \
    a3 = __builtin_amdgcn_mfma_f32_16x16x32_bf16(ae3, zfr[3][3], a3, 0, 0, 0); \
    __builtin_amdgcn_s_setprio(0); \
    const unsigned ibv = (unsigned)((ST) * (2 * NT)) + lanebase; \
    { const float k0 = __uint_as_float((__float_as_uint(a0[0]) & 0xFFFFC000u) | ibv); \
      const float k1 = __uint_as_float((__float_as_uint(a0[1]) & 0xFFFFC000u) | (ibv + 1)); \
      const float k2 = __uint_as_float((__float_as_uint(a0[2]) & 0xFFFFC000u) | (ibv + 2)); \
      const float k3 = __uint_as_float((__float_as_uint(a0[3]) & 0xFFFFC000u) | (ibv + 3)); \
      ins5f(tv0, fminf(fminf(k0, k1), fminf(k2, k3))); } \
    { const float k0 = __uint_as_float((__float_as_uint(a1[0]) & 0xFFFFC000u) | ibv); \
      const float k1 = __uint_as_float((__float_as_uint(a1[1]) & 0xFFFFC000u) | (ibv + 1)); \
      const float k2 = __uint_as_float((__float_as_uint(a1[2]) & 0xFFFFC000u) | (ibv + 2)); \
      const float k3 = __uint_as_float((__float_as_uint(a1[3]) & 0xFFFFC000u) | (ibv + 3)); \
      ins5f(tv1, fminf(fminf(k0, k1), fminf(k2, k3))); } \
    { const float k0 = __uint_as_float((__float_as_uint(a2[0]) & 0xFFFFC000u) | ibv); \
      const float k1 = __uint_as_float((__float_as_uint(a2[1]) & 0xFFFFC000u) | (ibv + 1)); \
      const float k2 = __uint_as_float((__float_as_uint(a2[2]) & 0xFFFFC000u) | (ibv + 2)); \
      const float k3 = __uint_as_float((__float_as_uint(a2[3]) & 0xFFFFC000u) | (ibv + 3)); \
      ins5f(tv2, fminf(fminf(k0, k1), fminf(k2, k3))); } \
    { const float k0 = __uint_as_float((__float_as_uint(a3[0]) & 0xFFFFC000u) | ibv); \
      const float k1 = __uint_as_float((__float_as_uint(a3[1]) & 0xFFFFC000u) | (ibv + 1)); \
      const float k2 = __uint_as_float((__float_as_uint(a3[2]) & 0xFFFFC000u) | (ibv + 2)); \
      const float k3 = __uint_as_float((__float_as_uint(a3[3]) & 0xFFFFC000u) | (ibv + 3)); \
      ins5f(tv3, fminf(fminf(k0, k1), fminf(k2, k3))); } \
    __builtin_amdgcn_s_barrier(); \
    asm volatile("" ::: "memory"); \
  } while (0)

  // Drain zfr register loads so manual vmcnt accounting is exact from here.
  asm volatile("s_waitcnt vmcnt(0)" ::: "memory");
  STAGE(0, cvA);   // super 0
  STAGE(1, cvB);   // super 1

  for (int ss = 0; ss < 23; ++ss) {
    PROCSUP(0, cvA, 2 * ss, 5);
    STAGE(0, cvA);             // super 2ss+2
    PROCSUP(1, cvB, 2 * ss + 1, 5);
    STAGE(1, cvB);             // super 2ss+3
  }
  PROCSUP(0, cvA, 46, 5);
  STAGE(0, cvA);               // super 48
  PROCSUP(1, cvB, 47, 5);
  PROCSUP(0, cvA, 48, 0);      // full drain

#undef STAGE
#undef PROCSUP

  // merge the 4 g-groups per q-row: butterfly over lanes ln^16, ln^32
  #pragma unroll
  for (int m = 16; m <= 32; m <<= 1) {
    float ov[5];
    #pragma unroll
    for (int q = 0; q < 5; ++q) ov[q] = __shfl_xor(tv0[q], m);
    #pragma unroll
    for (int q = 0; q < 5; ++q) ins5f(tv0, ov[q]);
    #pragma unroll
    for (int q = 0; q < 5; ++q) ov[q] = __shfl_xor(tv1[q], m);
    #pragma unroll
    for (int q = 0; q < 5; ++q) ins5f(tv1, ov[q]);
    #pragma unroll
    for (int q = 0; q < 5; ++q) ov[q] = __shfl_xor(tv2[q], m);
    #pragma unroll
    for (int q = 0; q < 5; ++q) ins5f(tv2, ov[q]);
    #pragma unroll
    for (int q = 0; q < 5; ++q) ov[q] = __shfl_xor(tv3[q], m);
    #pragma unroll
    for (int q = 0; q < 5; ++q) ins5f(tv3, ov[q]);
  }
  __syncthreads();   // full drain once before reusing Bsm as merge scratch
  float* mgk = reinterpret_cast<float*>(&Bsm[0][0][0]);   // [RQ=64][16][5] 20KB
  if (ln < 16) {
    #pragma unroll
    for (int q = 0; q < 5; ++q) {
      mgk[((0 + ln) * 16 + w) * Kk + q] = tv0[q];
      mgk[((16 + ln) * 16 + w) * Kk + q] = tv1[q];
      mgk[((32 + ln) * 16 + w) * Kk + q] = tv2[q];
      mgk[((48 + ln) * 16 + w) * Kk + q] = tv3[q];
    }
  }
  __syncthreads();
  if (tid < RQ) {
    float mv[5];
    #pragma unroll
    for (int q = 0; q < 5; ++q) mv[q] = mgk[(tid * 16 + 0) * Kk + q];
    for (int ww = 1; ww < 16; ++ww)
      #pragma unroll
      for (int q = 0; q < 5; ++q) ins5f(mv, mgk[(tid * 16 + ww) * Kk + q]);
    const size_t o = ((size_t)(rowBase + tid) * NCH8 + chunk) * Kk;
    #pragma unroll
    for (int q = 0; q < 5; ++q) {
      const unsigned u = __float_as_uint(mv[q]);
      candV[o + q] = __uint_as_float(u & 0xFFFFC000u);
      candI[o + q] = chunk * CH8 + (int)(u & 0x3FFFu);
    }
  }
}

// ---------------------------------------------------------------------------
// LEGACY PATH (round-3, verified): per-node scalars + in-loop cvt staging.
__global__ __launch_bounds__(256) void k_node(
    const float* __restrict__ emb, float* __restrict__ sArr, float* __restrict__ cArr)
{
  const int wv = threadIdx.x >> 6, ln = threadIdx.x & 63;
  const int node = blockIdx.x * 4 + wv;
  const float2 v = *reinterpret_cast<const float2*>(emb + (size_t)node * Dd + ln * 2);
  float t = v.x * v.x + v.y * v.y;
  #pragma unroll
  for (int off = 32; off > 0; off >>= 1) t += __shfl_xor(t, off);
  if (ln == 0) {
    const float E = fmaxf(sqrtf(t), EPSF);
    const float a = atanhf(fminf(E, MAXT));
    const float s = a / E;
    sArr[node] = s;
    cArr[node] = s * s * t;
  }
}

__global__ __launch_bounds__(512, 2) void k_topk16(
    const ushort* __restrict__ ztb, const float* __restrict__ emb,
    const float* __restrict__ sArr, const float* __restrict__ cArr,
    float* __restrict__ candV, int* __restrict__ candI)
{
  __shared__ __align__(16) ushort Bsm[2][NT * Dd];
  __shared__ __align__(16) float2 sclb[2][NT];
  __shared__ __align__(16) float mgv[RT][2][Kk];
  __shared__ int mgi[RT][2][Kk];

  const int tid = threadIdx.x;
  const int ln = tid & 63;
  const int wv = tid >> 6;
  const int ln15 = ln & 15;
  const int g = ln >> 4;
  const int wr = wv >> 1;
  const int wc = wv & 1;
  const int rowBase = blockIdx.x * RT;
  const int chunkStart = blockIdx.y * CH16;

  short8v afr[2][4];
  #pragma unroll
  for (int f = 0; f < 2; ++f)
    #pragma unroll
    for (int ks = 0; ks < 4; ++ks)
      afr[f][ks] = *reinterpret_cast<const short8v*>(
          ztb + (size_t)(rowBase + 32 * wr + 16 * f + ln15) * Dd + 32 * ks + 8 * g);

  int rdoff[4];
  #pragma unroll
  for (int ks = 0; ks < 4; ++ks)
    rdoff[ks] = (wc * 64 + ln15) * 256 + ((g * 16 + ks * 64) ^ ((ln15 & 7) << 4));

  f32x4 acc[2][4];
  #pragma unroll
  for (int f = 0; f < 2; ++f)
    #pragma unroll
    for (int c = 0; c < 4; ++c) acc[f][c] = (f32x4)0.f;

  float tv[8][5]; int ti[8][5];
  #pragma unroll
  for (int r = 0; r < 8; ++r)
    #pragma unroll
    for (int q = 0; q < 5; ++q) { tv[r][q] = 3.0e38f; ti[r][q] = 0x7fffffff; }

  float4 ld[8];

  auto stageLoad = [&](int t) {
    const int tStart = t * NT;
    const int left = CH16 - tStart;
    #pragma unroll
    for (int i = 0; i < 8; ++i) {
      const int flat = i * 512 + tid;
      const int nd = flat >> 5;
      float4 v = make_float4(0.f, 0.f, 0.f, 0.f);
      if (nd < left)
        v = *reinterpret_cast<const float4*>(
            emb + (size_t)(chunkStart + tStart + nd) * Dd + (flat & 31) * 4);
      ld[i] = v;
    }
  };

  auto stageWrite = [&](int t, int buf) {
    char* base = reinterpret_cast<char*>(&Bsm[buf][0]);
    #pragma unroll
    for (int i = 0; i < 8; ++i) {
      const int flat = i * 512 + tid;
      const int nd = flat >> 5;
      const int kb = (flat & 31) * 8;
      ushort4 w;
      w.x = f2bf(ld[i].x); w.y = f2bf(ld[i].y);
      w.z = f2bf(ld[i].z); w.w = f2bf(ld[i].w);
      *reinterpret_cast<ushort4*>(base + nd * 256 + (kb ^ ((nd & 7) << 4))) = w;
    }
    const int tStart = t * NT;
    const int left = CH16 - tStart;
    if (tid < NT) {
      const bool ok = tid < left;
      sclb[buf][tid] = make_float2(ok ? -2.f * sArr[chunkStart + tStart + tid] : 0.f,
                                   ok ? cArr[chunkStart + tStart + tid] : 3.0e38f);
    }
  };

  stageLoad(0);
  stageWrite(0, 0);
  __syncthreads();

  for (int t = 0; t < TIL16; ++t) {
    const int buf = t & 1;
    const bool have = (t + 1) < TIL16;
    if (have) stageLoad(t + 1);

    const char* bbase = reinterpret_cast<const char*>(&Bsm[buf][0]);
    #pragma unroll
    for (int c = 0; c < 4; ++c) {
      #pragma unroll
      for (int ks = 0; ks < 4; ++ks) {
        const short8v bfr = *reinterpret_cast<const short8v*>(bbase + c * 4096 + rdoff[ks]);
        acc[0][c] = __builtin_amdgcn_mfma_f32_16x16x32_bf16(afr[0][ks], bfr, acc[0][c], 0, 0, 0);
        acc[1][c] = __builtin_amdgcn_mfma_f32_16x16x32_bf16(afr[1][ks], bfr, acc[1][c], 0, 0, 0);
      }
    }

    if (have) stageWrite(t + 1, buf ^ 1);

    #pragma unroll
    for (int c = 0; c < 4; ++c) {
      const int nl = wc * 64 + c * 16 + ln15;
      const float2 sc2 = sclb[buf][nl];
      const int node = chunkStart + t * NT + nl;
      #pragma unroll
      for (int f = 0; f < 2; ++f) {
        #pragma unroll
        for (int i = 0; i < 4; ++i) {
          const float v = fmaf(sc2.x, acc[f][c][i], sc2.y);
          INS5(tv[f * 4 + i], ti[f * 4 + i], v, node);
        }
        acc[f][c] = (f32x4)0.f;
      }
    }
    __syncthreads();
  }

  #pragma unroll
  for (int m = 1; m <= 8; m <<= 1) {
    #pragma unroll
    for (int r = 0; r < 8; ++r) {
      float ov[5]; int oi[5];
      #pragma unroll
      for (int q = 0; q < 5; ++q) {
        ov[q] = __shfl_xor(tv[r][q], m);
        oi[q] = __shfl_xor(ti[r][q], m);
      }
      #pragma unroll
      for (int q = 0; q < 5; ++q) INS5L(tv[r], ti[r], ov[q], oi[q]);
    }
  }
  if (ln15 == 0) {
    #pragma unroll
    for (int f = 0; f < 2; ++f)
      #pragma unroll
      for (int i = 0; i < 4; ++i) {
        const int row = 32 * wr + 16 * f + 4 * g + i;
        #pragma unroll
        for (int q = 0; q < 5; ++q) {
          mgv[row][wc][q] = tv[f * 4 + i][q];
          mgi[row][wc][q] = ti[f * 4 + i][q];
        }
      }
  }
  __syncthreads();
  if (tid < RT) {
    float mv[5]; int mi[5];
    #pragma unroll
    for (int q = 0; q < 5; ++q) { mv[q] = mgv[tid][0][q]; mi[q] = mgi[tid][0][q]; }
    #pragma unroll
    for (int q = 0; q < 5; ++q) INS5L(mv, mi, mgv[tid][1][q], mgi[tid][1][q]);
    const size_t o = ((size_t)(rowBase + tid) * NCH16 + blockIdx.y) * Kk;
    #pragma unroll
    for (int q = 0; q < 5; ++q) { candV[o + q] = mv[q]; candI[o + q] = mi[q]; }
  }
}

// ---------------------------------------------------------------------------
// Kernel 4 (shared): wave-per-row final merge -> gather-mean -> mobius_add.
__global__ __launch_bounds__(256) void k_fuse(
    const float* __restrict__ emb, const float* __restrict__ candV,
    const int* __restrict__ candI, const float* __restrict__ zhyp,
    float* __restrict__ out, int ncand)
{
  const int wv = threadIdx.x >> 6, ln = threadIdx.x & 63;
  const int row = blockIdx.x * 4 + wv;

  float mv[5]; int mi[5];
  #pragma unroll
  for (int q = 0; q < 5; ++q) { mv[q] = 3.0e38f; mi[q] = 0x7fffffff; }
  const size_t base = (size_t)row * ncand;
  for (int j = ln; j < ncand; j += 64) INS5L(mv, mi, candV[base + j], candI[base + j]);
  #pragma unroll
  for (int m = 1; m <= 32; m <<= 1) {
    float ov[5]; int oi[5];
    #pragma unroll
    for (int q = 0; q < 5; ++q) { ov[q] = __shfl_xor(mv[q], m); oi[q] = __shfl_xor(mi[q], m); }
    #pragma unroll
    for (int q = 0; q < 5; ++q) INS5L(mv, mi, ov[q], oi[q]);
  }
  // all lanes now hold the identical global top-5 indices
  float y0 = 0.f, y1 = 0.f;
  #pragma unroll
  for (int q = 0; q < Kk; ++q) {
    const float* e = emb + (size_t)mi[q] * Dd;
    y0 += e[ln]; y1 += e[ln + 64];
  }
  y0 *= 0.2f; y1 *= 0.2f;
  const float x0 = zhyp[(size_t)row * Dd + ln];
  const float x1 = zhyp[(size_t)row * Dd + ln + 64];
  float x2 = x0 * x0 + x1 * x1;
  float y2 = y0 * y0 + y1 * y1;
  float xy = x0 * y0 + x1 * y1;
  #pragma unroll
  for (int off = 32; off > 0; off >>= 1) {
    x2 += __shfl_xor(x2, off);
    y2 += __shfl_xor(y2, off);
    xy += __shfl_xor(xy, off);
  }
  const float ca = 1.f + 2.f * xy + y2;
  const float cb2 = 1.f - x2;
  const float den = 1.f / (1.f + 2.f * xy + x2 * y2 + EPSF);
  out[(size_t)row * Dd + ln] = (ca * x0 + cb2 * y0) * den;
  out[(size_t)row * Dd + ln + 64] = (ca * x1 + cb2 * y1) * den;
}

// ---------------------------------------------------------------------------
extern "C" void kernel_launch(void* const* d_in, const int* in_sizes, int n_in,
                              void* d_out, int out_size, void* d_ws, size_t ws_size,
                              hipStream_t stream)
{
  (void)in_sizes; (void)n_in; (void)out_size;
  const float* zseq = (const float*)d_in[0];
  const float* emb  = (const float*)d_in[1];
  const float* W    = (const float*)d_in[2];
  const float* bias = (const float*)d_in[3];
  float* out = (float*)d_out;            // [z_fused (B*D) | z_hyp (B*D)] f32

  const size_t ztbBytes   = (size_t)Bb * Dd * 2;                  // 524288
  const size_t embswBytes = (size_t)NCH8 * TIL8 * TILE_BYTES;     // 25690112
  const size_t cpadBytes  = (size_t)NCH8 * PAD8 * 4;              // 401408
  const size_t candVBytes = (size_t)Bb * NCH8 * Kk * 4;           // 327680
  const size_t needFast = ztbBytes + embswBytes + cpadBytes + 2 * candVBytes;

  if (ws_size >= needFast) {
    char* ws = (char*)d_ws;
    ushort* ztb   = (ushort*)ws;
    ushort* embsw = (ushort*)(ws + ztbBytes);
    float*  cpad  = (float*)(ws + ztbBytes + embswBytes);
    float*  candV = (float*)(ws + ztbBytes + embswBytes + cpadBytes);
    int*    candI = (int*)(ws + ztbBytes + embswBytes + cpadBytes + candVBytes);

    hipLaunchKernelGGL(k_prep, dim3(Bb / 8 + NCH8 * PAD8 / 8), dim3(256), 0,
                       stream, zseq, W, bias, out + HALF, ztb, emb, embsw, cpad);
    hipLaunchKernelGGL(k_topk8, dim3(256), dim3(1024), 0, stream,
                       ztb, embsw, cpad, candV, candI);
    hipLaunchKernelGGL(k_fuse, dim3(Bb / 4), dim3(256), 0, stream,
                       emb, candV, candI, out + HALF, out, NCH8 * Kk);
  } else {
    char* ws = (char*)d_ws;
    ushort* ztb  = (ushort*)ws;
    float* sArr  = (float*)(ws + ztbBytes);
    float* cArr  = sArr + Nn;
    float* candV = cArr + Nn;
    int*   candI = (int*)(candV + (size_t)Bb * NCH16 * Kk);

    hipLaunchKernelGGL(k_proj, dim3(Bb / 8), dim3(256), 0, stream,
                       zseq, W, bias, out + HALF, ztb);
    hipLaunchKernelGGL(k_node, dim3(Nn / 4), dim3(256), 0, stream, emb, sArr, cArr);
    hipLaunchKernelGGL(k_topk16, dim3(Bb / RT, NCH16), dim3(512), 0, stream,
                       ztb, emb, sArr, cArr, candV, candI);
    hipLaunchKernelGGL(k_fuse, dim3(Bb / 4), dim3(256), 0, stream,
                       emb, candV, candI, out + HALF, out, NCH16 * Kk);
  }
}

// Round 18
// 116.457 us; speedup vs baseline: 2.7929x; 2.7929x over previous
//
#include <hip/hip_runtime.h>
#include <hip/hip_bf16.h>
#include <math.h>

#define EPSF 1e-7f
#define MAXT 0.99999f   // 1 - 1e-5

typedef __attribute__((ext_vector_type(8))) short short8v;   // 8 x bf16 (4 VGPR)
typedef __attribute__((ext_vector_type(4))) float f32x4;     // MFMA C/D frag

constexpr int Bb = 2048;
constexpr int Ss = 768;
constexpr int Dd = 128;
constexpr int Nn = 100000;
constexpr int Kk = 5;
constexpr int HALF = Bb * Dd;        // 262144
constexpr int NT = 128;              // nodes per tile
constexpr int TILE_BYTES = NT * Dd * 2;  // 32768
constexpr int SUP_BYTES = 2 * TILE_BYTES;  // 64KB super-tile (2 tiles)
constexpr float SBIAS = 16.0f;       // score-positivity bias (|2 s dot| < 12.5)

// fast path: transposed MFMA (A=emb', B=z), 8 chunks of 12500, 98 tiles/chunk
constexpr int NCH8 = 8;
constexpr int CH8 = Nn / NCH8;       // 12500
constexpr int TIL8 = 98;             // tiles/chunk; 49 super-tiles exactly
constexpr int NSUP = TIL8 / 2;       // 49
constexpr int PAD8 = TIL8 * NT;      // 12544 padded slots per chunk (fits 14 bits)
constexpr int RQ = 64;               // query rows per block (2 q-halves share LDS)

// legacy path (round-3, verified): 16 chunks of 6250, in-loop cvt staging
constexpr int NCH16 = 16;
constexpr int CH16 = Nn / NCH16;     // 6250
constexpr int TIL16 = (CH16 + NT - 1) / NT;  // 49
constexpr int RT = 128;

static __device__ __forceinline__ ushort f2bf(float x) {
  __hip_bfloat16 h = __float2bfloat16(x);
  return *reinterpret_cast<ushort*>(&h);
}

static __device__ __forceinline__ float med3f(float a, float b, float c) {
  float r;
  asm("v_med3_f32 %0, %1, %2, %3" : "=v"(r) : "v"(a), "v"(b), "v"(c));
  return r;
}

// Branchless insert of v into ascending sorted k[0..4], keep 5 smallest.
// Keys are positive finite floats whose uint order == float order.
static __device__ __forceinline__ void ins5f(float* k, float v) {
  const float n0 = fminf(k[0], v);
  const float n1 = med3f(k[0], k[1], v);
  const float n2 = med3f(k[1], k[2], v);
  const float n3 = med3f(k[2], k[3], v);
  const float n4 = med3f(k[3], k[4], v);
  k[0] = n0; k[1] = n1; k[2] = n2; k[3] = n3; k[4] = n4;
}

// Insert into ascending-sorted top-5 (value,index) — legacy path only.
#define INS5(TV, TI, V, ID) do { \
  const float _v = (V); const int _id = (ID); \
  if (_v < TV[4]) { \
    TV[4] = _v; TI[4] = _id; \
    if (TV[4] < TV[3]) { float _t=TV[3];TV[3]=TV[4];TV[4]=_t;int _u=TI[3];TI[3]=TI[4];TI[4]=_u; } \
    if (TV[3] < TV[2]) { float _t=TV[2];TV[2]=TV[3];TV[3]=_t;int _u=TI[2];TI[2]=TI[3];TI[3]=_u; } \
    if (TV[2] < TV[1]) { float _t=TV[1];TV[1]=TV[2];TV[2]=_t;int _u=TI[1];TI[1]=TI[2];TI[2]=_u; } \
    if (TV[1] < TV[0]) { float _t=TV[0];TV[0]=TV[1];TV[1]=_t;int _u=TI[0];TI[0]=TI[1];TI[1]=_u; } \
  } } while(0)

// Lexicographic (value, index) insert for merging unordered candidate streams.
#define LXLT(V,I,V2,I2) ((V) < (V2) || ((V) == (V2) && (I) < (I2)))
#define INS5L(TV, TI, V, ID) do { \
  const float _v = (V); const int _id = (ID); \
  if (LXLT(_v,_id,TV[4],TI[4])) { \
    TV[4]=_v; TI[4]=_id; \
    if (LXLT(TV[4],TI[4],TV[3],TI[3])) { float _t=TV[3];TV[3]=TV[4];TV[4]=_t;int _u=TI[3];TI[3]=TI[4];TI[4]=_u; } \
    if (LXLT(TV[3],TI[3],TV[2],TI[2])) { float _t=TV[2];TV[2]=TV[3];TV[3]=_t;int _u=TI[2];TI[2]=TI[3];TI[3]=_u; } \
    if (LXLT(TV[2],TI[2],TV[1],TI[1])) { float _t=TV[1];TV[1]=TV[2];TV[2]=_t;int _u=TI[1];TI[1]=TI[2];TI[2]=_u; } \
    if (LXLT(TV[1],TI[1],TV[0],TI[0])) { float _t=TV[0];TV[0]=TV[1];TV[1]=_t;int _u=TI[0];TI[0]=TI[1];TI[1]=_u; } \
  } } while(0)

// ---------------------------------------------------------------------------
// Shared proj body: 8 rows, 256 threads split-K.
static __device__ __forceinline__ void proj_body(
    const float* __restrict__ zseq, const float* __restrict__ W,
    const float* __restrict__ bias, float* __restrict__ outH,
    ushort* __restrict__ ztb, int blk,
    float (*zrow)[768], float (*zp)[128], float (*php)[128], float* rno)
{
  const int tid = threadIdx.x;
  const int d = tid & 127, h = tid >> 7;
  const int r0 = blk * 8;

  {
    const float4* src = reinterpret_cast<const float4*>(zseq + (size_t)r0 * Ss);
    float4* dst = reinterpret_cast<float4*>(&zrow[0][0]);
    #pragma unroll
    for (int i = 0; i < 6; ++i) dst[i * 256 + tid] = src[i * 256 + tid];
  }
  __syncthreads();

  float acc[8];
  #pragma unroll
  for (int r = 0; r < 8; ++r) acc[r] = 0.f;
  const float4* w4 = reinterpret_cast<const float4*>(W + (size_t)d * Ss) + h * 96;
  for (int j = 0; j < 96; ++j) {
    const float4 w = w4[j];
    const int kb = h * 384 + j * 4;
    #pragma unroll
    for (int r = 0; r < 8; ++r) {
      const float4 z = *reinterpret_cast<const float4*>(&zrow[r][kb]);
      acc[r] = fmaf(z.x, w.x, acc[r]);
      acc[r] = fmaf(z.y, w.y, acc[r]);
      acc[r] = fmaf(z.z, w.z, acc[r]);
      acc[r] = fmaf(z.w, w.w, acc[r]);
    }
  }
  #pragma unroll
  for (int r = 0; r < 8; ++r) {
    if (h == 0) zp[r][d] = acc[r]; else php[r][d] = acc[r];
  }
  __syncthreads();
  if (tid < 128) {
    const float bv = bias[d];
    #pragma unroll
    for (int r = 0; r < 8; ++r) zp[r][d] = zp[r][d] + php[r][d] + bv;
  }
  __syncthreads();

  const int wv = tid >> 6, ln = tid & 63;
  if (tid < 128) {
    #pragma unroll
    for (int rr = 0; rr < 4; ++rr) {
      const int r = wv * 4 + rr;
      float v = zp[r][ln] * zp[r][ln] + zp[r][ln + 64] * zp[r][ln + 64];
      #pragma unroll
      for (int off = 32; off > 0; off >>= 1) v += __shfl_xor(v, off);
      if (ln == 0) rno[r] = v;
    }
  }
  __syncthreads();
  if (tid < 128) {
    #pragma unroll
    for (int r = 0; r < 8; ++r) {
      const float n = fmaxf(sqrtf(rno[r]), EPSF);
      const float zh = tanhf(n) * zp[r][d] / n;
      outH[(size_t)(r0 + r) * Dd + d] = zh;   // z_hyp output (f32)
      zp[r][d] = zh;
    }
  }
  __syncthreads();
  if (tid < 128) {
    #pragma unroll
    for (int rr = 0; rr < 4; ++rr) {
      const int r = wv * 4 + rr;
      float v = zp[r][ln] * zp[r][ln] + zp[r][ln + 64] * zp[r][ln + 64];
      #pragma unroll
      for (int off = 32; off > 0; off >>= 1) v += __shfl_xor(v, off);
      if (ln == 0) rno[r] = v;
    }
  }
  __syncthreads();
  if (tid < 128) {
    #pragma unroll
    for (int r = 0; r < 8; ++r) {
      const float m = fmaxf(sqrtf(rno[r]), EPSF);
      const float a = atanhf(fminf(m, MAXT));
      ztb[(size_t)(r0 + r) * Dd + d] = f2bf(a * zp[r][d] / m);
    }
  }
}

// Legacy-path standalone proj.
__global__ __launch_bounds__(256) void k_proj(
    const float* __restrict__ zseq, const float* __restrict__ W,
    const float* __restrict__ bias, float* __restrict__ outH,
    ushort* __restrict__ ztb)
{
  __shared__ __align__(16) float zrow[8][768];
  __shared__ float zp[8][128];
  __shared__ float php[8][128];
  __shared__ float rno[8];
  proj_body(zseq, W, bias, outH, ztb, blockIdx.x, zrow, zp, php, rno);
}

// ---------------------------------------------------------------------------
// FAST PATH fused prep: blocks [0,256) run proj; blocks [256,...) run pack.
// Pack: 2 nodes per wave (per-lane float4, 32-lane-half reduce). emb' =
// bf16(-2*s_n*emb_n), XOR-SWIZZLED tiled image (byte ^= (node&7)<<4).
// cpad[slot] = c_n + SBIAS or +INF for pad slots.
__global__ __launch_bounds__(256) void k_prep(
    const float* __restrict__ zseq, const float* __restrict__ W,
    const float* __restrict__ bias, float* __restrict__ outH,
    ushort* __restrict__ ztb, const float* __restrict__ emb,
    ushort* __restrict__ embsw, float* __restrict__ cpad)
{
  __shared__ __align__(16) float zrow[8][768];
  __shared__ float zp[8][128];
  __shared__ float php[8][128];
  __shared__ float rno[8];

  if (blockIdx.x < Bb / 8) {
    proj_body(zseq, W, bias, outH, ztb, blockIdx.x, zrow, zp, php, rno);
    return;
  }

  // ---- pack part: wave handles 2 nodes (32-lane half each, float4/lane)
  const int wv = threadIdx.x >> 6, ln = threadIdx.x & 63;
  const int half = ln >> 5, l5 = ln & 31;
  const int p = (blockIdx.x - Bb / 8) * 8 + wv * 2 + half;   // padded slot
  const int chunk = p / PAD8;
  const int local = p - chunk * PAD8;
  const bool real = local < CH8;
  const int node = chunk * CH8 + local;
  float4 v = make_float4(0.f, 0.f, 0.f, 0.f);
  if (real) v = *reinterpret_cast<const float4*>(emb + (size_t)node * Dd + l5 * 4);
  float t = v.x * v.x + v.y * v.y + v.z * v.z + v.w * v.w;
  #pragma unroll
  for (int off = 16; off > 0; off >>= 1) t += __shfl_xor(t, off);  // within half

  const float E = fmaxf(sqrtf(t), EPSF);
  const float a = atanhf(fminf(E, MAXT));
  const float s = a / E;
  const float m2s = -2.f * s;

  const int tt = local >> 7, nd = local & 127;
  ushort4 w;
  w.x = f2bf(m2s * v.x); w.y = f2bf(m2s * v.y);
  w.z = f2bf(m2s * v.z); w.w = f2bf(m2s * v.w);
  char* dst = reinterpret_cast<char*>(embsw)
            + ((size_t)((chunk * TIL8 + tt) * NT + nd) << 8)
            + ((l5 * 8) ^ ((nd & 7) << 4));
  *reinterpret_cast<ushort4*>(dst) = w;

  if (l5 == 0) cpad[p] = real ? (s * s * t + SBIAS) : 3.0e38f;
}

// ---------------------------------------------------------------------------
// FAST PATH topk (R16 verified optimum): super-tile LDS staging via
// global_load_lds + XCD pinning + counted vmcnt + register c-values +
// min-reduce med3 epilogue. 1024 threads (16 waves, 2 q-halves), 256 blocks,
// chunk = bid&7, LDS 128KB, 1 block/CU, 4 waves/SIMD.
__global__ __launch_bounds__(1024, 4) void k_topk8(
    const ushort* __restrict__ ztb, const ushort* __restrict__ embsw,
    const float* __restrict__ cpad, float* __restrict__ candV,
    int* __restrict__ candI)
{
  __shared__ __align__(16) ushort Bsm[2][2][NT * Dd];  // 2 super-bufs x 2 tiles

  const int tid = threadIdx.x;
  const int ln = tid & 63;
  const int wv8 = (tid >> 6) & 7;   // node sub-slice (16 nodes)
  const int qh = tid >> 9;          // q-half: waves 0-7 -> 0, 8-15 -> 1
  const int ln15 = ln & 15;
  const int g = ln >> 4;            // 0..3
  const int chunk = blockIdx.x & 7;            // XCD-pinned chunk (proven R8)
  const int rowBase = (blockIdx.x >> 3) * RQ;
  const int qBase = rowBase + qh * 32;
  const char* embc = reinterpret_cast<const char*>(embsw)
                   + (size_t)chunk * (TIL8 * TILE_BYTES);
  const float* cch = cpad + (size_t)chunk * PAD8;

  // B operand: z fragments for this wave's 32 q-rows, reused all tiles.
  short8v zfr[2][4];
  #pragma unroll
  for (int f = 0; f < 2; ++f)
    #pragma unroll
    for (int ks = 0; ks < 4; ++ks)
      zfr[f][ks] = *reinterpret_cast<const short8v*>(
          ztb + (size_t)(qBase + 16 * f + ln15) * Dd + 32 * ks + 8 * g);

  // A operand LDS byte offsets (SWIZZLED): node = wv8*16+ln15, k = 32ks+8g
  int rdoff[4];
  #pragma unroll
  for (int ks = 0; ks < 4; ++ks)
    rdoff[ks] = (wv8 * 16 + ln15) * 256 + ((ks * 64 + g * 16) ^ ((ln15 & 7) << 4));
  const unsigned lanebase = (unsigned)(wv8 * 16 + 4 * g);

  float tv0[5], tv1[5];
  const float KINIT = __uint_as_float(0x7F7FFFFFu);   // max finite float
  #pragma unroll
  for (int q = 0; q < 5; ++q) { tv0[q] = KINIT; tv1[q] = KINIT; }

  // rolling staging pointers (advance one SUPER-tile per STAGE).
  const char* srcP = embc + tid * 16;
  unsigned long long cvP =
      (unsigned long long)(cch + wv8 * 16 + 4 * g);   // lane's 4 c floats

  f32x4 cvA0, cvA1, cvB0, cvB1;   // per-tile biased c (register double-buffer)

#define STAGE(BB, CV0, CV1) do { \
    char* lb = reinterpret_cast<char*>(&Bsm[BB][0][0]) + tid * 16; \
    __builtin_amdgcn_global_load_lds( \
        (const __attribute__((address_space(1))) unsigned int*)(srcP), \
        (__attribute__((address_space(3))) unsigned int*)(lb), 16, 0, 0); \
    __builtin_amdgcn_global_load_lds( \
        (const __attribute__((address_space(1))) unsigned int*)(srcP + 16384), \
        (__attribute__((address_space(3))) unsigned int*)(lb + 16384), 16, 0, 0); \
    __builtin_amdgcn_global_load_lds( \
        (const __attribute__((address_space(1))) unsigned int*)(srcP + 32768), \
        (__attribute__((address_space(3))) unsigned int*)(lb + 32768), 16, 0, 0); \
    __builtin_amdgcn_global_load_lds( \
        (const __attribute__((address_space(1))) unsigned int*)(srcP + 49152), \
        (__attribute__((address_space(3))) unsigned int*)(lb + 49152), 16, 0, 0); \
    asm volatile("global_load_dwordx4 %0, %2, off\n\t" \
                 "global_load_dwordx4 %1, %3, off" \
        : "=&v"(CV0), "=&v"(CV1) \
        : "v"(cvP), "v"(cvP + (unsigned long long)(NT * 4))); \
    srcP += SUP_BYTES; \
    cvP += (unsigned long long)(2 * NT * 4); } while (0)

#define TILEBODY(BB, UU, CV, IBV, MM0, MM1) do { \
    const char* bbase = reinterpret_cast<const char*>(&Bsm[BB][UU][0]); \
    const short8v ae0 = *reinterpret_cast<const short8v*>(bbase + rdoff[0]); \
    const short8v ae1 = *reinterpret_cast<const short8v*>(bbase + rdoff[1]); \
    const short8v ae2 = *reinterpret_cast<const short8v*>(bbase + rdoff[2]); \
    const short8v ae3 = *reinterpret_cast<const short8v*>(bbase + rdoff[3]); \
    __builtin_amdgcn_s_setprio(1); \
    f32x4 a0 = __builtin_amdgcn_mfma_f32_16x16x32_bf16(ae0, zfr[0][0], CV, 0, 0, 0); \
    f32x4 a1 = __builtin_amdgcn_mfma_f32_16x16x32_bf16(ae0, zfr[1][0], CV, 0, 0, 0); \
    a0 = __builtin_amdgcn_mfma_f32_16x16x32_bf16(ae1, zfr[0][1], a0, 0, 0, 0); \
    a1 = __builtin_amdgcn_mfma_f32_16x16x32_bf16(ae1, zfr[1][1], a1, 0, 0, 0); \
    a0 = __builtin_amdgcn_mfma_f32_16x16x32_bf16(ae2, zfr[0][2], a0, 0, 0, 0); \
    a1 = __builtin_amdgcn_mfma_f32_16x16x32_bf16(ae2, zfr[1][2], a1, 0, 0, 0); \
    a0 = __builtin_amdgcn_mfma_f32_16x16x32_bf16(ae3, zfr[0][3], a0, 0, 0, 0); \
    a1 = __builtin_amdgcn_mfma_f32_16x16x32_bf16(ae3, zfr[1][3], a1, 0, 0, 0); \
    __builtin_amdgcn_s_setprio(0); \
    const unsigned ibv = (IBV); \
    { const float k0 = __uint_as_float((__float_as_uint(a0[0]) & 0xFFFFC000u) | ibv); \
      const float k1 = __uint_as_float((__float_as_uint(a0[1]) & 0xFFFFC000u) | (ibv + 1)); \
      const float k2 = __uint_as_float((__float_as_uint(a0[2]) & 0xFFFFC000u) | (ibv + 2)); \
      const float k3 = __uint_as_float((__float_as_uint(a0[3]) & 0xFFFFC000u) | (ibv + 3)); \
      MM0 = fminf(MM0, fminf(fminf(k0, k1), fminf(k2, k3))); } \
    { const float k0 = __uint_as_float((__float_as_uint(a1[0]) & 0xFFFFC000u) | ibv); \
      const float k1 = __uint_as_float((__float_as_uint(a1[1]) & 0xFFFFC000u) | (ibv + 1)); \
      const float k2 = __uint_as_float((__float_as_uint(a1[2]) & 0xFFFFC000u) | (ibv + 2)); \
      const float k3 = __uint_as_float((__float_as_uint(a1[3]) & 0xFFFFC000u) | (ibv + 3)); \
      MM1 = fminf(MM1, fminf(fminf(k0, k1), fminf(k2, k3))); } \
  } while (0)

#define PROCSUP(BB, CV0, CV1, ST, WN) do { \
    asm volatile("s_waitcnt vmcnt(" #WN ")" ::: "memory"); \
    __builtin_amdgcn_sched_barrier(0); \
    __builtin_amdgcn_s_barrier(); \
    float mm0 = KINIT, mm1 = KINIT; \
    TILEBODY(BB, 0, CV0, (unsigned)((2 * (ST)) * NT) + lanebase, mm0, mm1); \
    TILEBODY(BB, 1, CV1, (unsigned)((2 * (ST) + 1) * NT) + lanebase, mm0, mm1); \
    ins5f(tv0, mm0); \
    ins5f(tv1, mm1); \
    __builtin_amdgcn_s_barrier(); \
    asm volatile("" ::: "memory"); \
  } while (0)

  // Drain zfr register loads so manual vmcnt accounting is exact from here.
  asm volatile("s_waitcnt vmcnt(0)" ::: "memory");
  STAGE(0, cvA0, cvA1);   // super 0
  STAGE(1, cvB0, cvB1);   // super 1

  for (int ss = 0; ss < 23; ++ss) {
    PROCSUP(0, cvA0, cvA1, 2 * ss, 6);
    STAGE(0, cvA0, cvA1);             // super 2ss+2
    PROCSUP(1, cvB0, cvB1, 2 * ss + 1, 6);
    STAGE(1, cvB0, cvB1);             // super 2ss+3
  }
  PROCSUP(0, cvA0, cvA1, 46, 6);
  STAGE(0, cvA0, cvA1);               // super 48
  PROCSUP(1, cvB0, cvB1, 47, 6);
  PROCSUP(0, cvA0, cvA1, 48, 0);      // full drain

#undef STAGE
#undef TILEBODY
#undef PROCSUP

  // merge the 4 g-groups per (q, wave): butterfly over lanes ln^16, ln^32
  #pragma unroll
  for (int m = 16; m <= 32; m <<= 1) {
    float ov[5];
    #pragma unroll
    for (int q = 0; q < 5; ++q) ov[q] = __shfl_xor(tv0[q], m);
    #pragma unroll
    for (int q = 0; q < 5; ++q) ins5f(tv0, ov[q]);
    #pragma unroll
    for (int q = 0; q < 5; ++q) ov[q] = __shfl_xor(tv1[q], m);
    #pragma unroll
    for (int q = 0; q < 5; ++q) ins5f(tv1, ov[q]);
  }
  __syncthreads();   // full drain once before reusing Bsm as merge scratch
  float* mgk = reinterpret_cast<float*>(&Bsm[0][0][0]);     // [RQ=64][8][5]
  if (ln < 16) {
    #pragma unroll
    for (int q = 0; q < 5; ++q) {
      mgk[((qh * 32 + 0 + ln) * 8 + wv8) * Kk + q] = tv0[q];
      mgk[((qh * 32 + 16 + ln) * 8 + wv8) * Kk + q] = tv1[q];
    }
  }
  __syncthreads();
  if (tid < RQ) {
    float mv[5];
    #pragma unroll
    for (int q = 0; q < 5; ++q) mv[q] = mgk[(tid * 8 + 0) * Kk + q];
    for (int w = 1; w < 8; ++w)
      #pragma unroll
      for (int q = 0; q < 5; ++q) ins5f(mv, mgk[(tid * 8 + w) * Kk + q]);
    const size_t o = ((size_t)(rowBase + tid) * NCH8 + chunk) * Kk;
    #pragma unroll
    for (int q = 0; q < 5; ++q) {
      const unsigned u = __float_as_uint(mv[q]);
      candV[o + q] = __uint_as_float(u & 0xFFFFC000u);
      candI[o + q] = chunk * CH8 + (int)(u & 0x3FFFu);
    }
  }
}

// ---------------------------------------------------------------------------
// LEGACY PATH (round-3, verified): per-node scalars + in-loop cvt staging.
__global__ __launch_bounds__(256) void k_node(
    const float* __restrict__ emb, float* __restrict__ sArr, float* __restrict__ cArr)
{
  const int wv = threadIdx.x >> 6, ln = threadIdx.x & 63;
  const int node = blockIdx.x * 4 + wv;
  const float2 v = *reinterpret_cast<const float2*>(emb + (size_t)node * Dd + ln * 2);
  float t = v.x * v.x + v.y * v.y;
  #pragma unroll
  for (int off = 32; off > 0; off >>= 1) t += __shfl_xor(t, off);
  if (ln == 0) {
    const float E = fmaxf(sqrtf(t), EPSF);
    const float a = atanhf(fminf(E, MAXT));
    const float s = a / E;
    sArr[node] = s;
    cArr[node] = s * s * t;
  }
}

__global__ __launch_bounds__(512, 2) void k_topk16(
    const ushort* __restrict__ ztb, const float* __restrict__ emb,
    const float* __restrict__ sArr, const float* __restrict__ cArr,
    float* __restrict__ candV, int* __restrict__ candI)
{
  __shared__ __align__(16) ushort Bsm[2][NT * Dd];
  __shared__ __align__(16) float2 sclb[2][NT];
  __shared__ __align__(16) float mgv[RT][2][Kk];
  __shared__ int mgi[RT][2][Kk];

  const int tid = threadIdx.x;
  const int ln = tid & 63;
  const int wv = tid >> 6;
  const int ln15 = ln & 15;
  const int g = ln >> 4;
  const int wr = wv >> 1;
  const int wc = wv & 1;
  const int rowBase = blockIdx.x * RT;
  const int chunkStart = blockIdx.y * CH16;

  short8v afr[2][4];
  #pragma unroll
  for (int f = 0; f < 2; ++f)
    #pragma unroll
    for (int ks = 0; ks < 4; ++ks)
      afr[f][ks] = *reinterpret_cast<const short8v*>(
          ztb + (size_t)(rowBase + 32 * wr + 16 * f + ln15) * Dd + 32 * ks + 8 * g);

  int rdoff[4];
  #pragma unroll
  for (int ks = 0; ks < 4; ++ks)
    rdoff[ks] = (wc * 64 + ln15) * 256 + ((g * 16 + ks * 64) ^ ((ln15 & 7) << 4));

  f32x4 acc[2][4];
  #pragma unroll
  for (int f = 0; f < 2; ++f)
    #pragma unroll
    for (int c = 0; c < 4; ++c) acc[f][c] = (f32x4)0.f;

  float tv[8][5]; int ti[8][5];
  #pragma unroll
  for (int r = 0; r < 8; ++r)
    #pragma unroll
    for (int q = 0; q < 5; ++q) { tv[r][q] = 3.0e38f; ti[r][q] = 0x7fffffff; }

  float4 ld[8];

  auto stageLoad = [&](int t) {
    const int tStart = t * NT;
    const int left = CH16 - tStart;
    #pragma unroll
    for (int i = 0; i < 8; ++i) {
      const int flat = i * 512 + tid;
      const int nd = flat >> 5;
      float4 v = make_float4(0.f, 0.f, 0.f, 0.f);
      if (nd < left)
        v = *reinterpret_cast<const float4*>(
            emb + (size_t)(chunkStart + tStart + nd) * Dd + (flat & 31) * 4);
      ld[i] = v;
    }
  };

  auto stageWrite = [&](int t, int buf) {
    char* base = reinterpret_cast<char*>(&Bsm[buf][0]);
    #pragma unroll
    for (int i = 0; i < 8; ++i) {
      const int flat = i * 512 + tid;
      const int nd = flat >> 5;
      const int kb = (flat & 31) * 8;
      ushort4 w;
      w.x = f2bf(ld[i].x); w.y = f2bf(ld[i].y);
      w.z = f2bf(ld[i].z); w.w = f2bf(ld[i].w);
      *reinterpret_cast<ushort4*>(base + nd * 256 + (kb ^ ((nd & 7) << 4))) = w;
    }
    const int tStart = t * NT;
    const int left = CH16 - tStart;
    if (tid < NT) {
      const bool ok = tid < left;
      sclb[buf][tid] = make_float2(ok ? -2.f * sArr[chunkStart + tStart + tid] : 0.f,
                                   ok ? cArr[chunkStart + tStart + tid] : 3.0e38f);
    }
  };

  stageLoad(0);
  stageWrite(0, 0);
  __syncthreads();

  for (int t = 0; t < TIL16; ++t) {
    const int buf = t & 1;
    const bool have = (t + 1) < TIL16;
    if (have) stageLoad(t + 1);

    const char* bbase = reinterpret_cast<const char*>(&Bsm[buf][0]);
    #pragma unroll
    for (int c = 0; c < 4; ++c) {
      #pragma unroll
      for (int ks = 0; ks < 4; ++ks) {
        const short8v bfr = *reinterpret_cast<const short8v*>(bbase + c * 4096 + rdoff[ks]);
        acc[0][c] = __builtin_amdgcn_mfma_f32_16x16x32_bf16(afr[0][ks], bfr, acc[0][c], 0, 0, 0);
        acc[1][c] = __builtin_amdgcn_mfma_f32_16x16x32_bf16(afr[1][ks], bfr, acc[1][c], 0, 0, 0);
      }
    }

    if (have) stageWrite(t + 1, buf ^ 1);

    #pragma unroll
    for (int c = 0; c < 4; ++c) {
      const int nl = wc * 64 + c * 16 + ln15;
      const float2 sc2 = sclb[buf][nl];
      const int node = chunkStart + t * NT + nl;
      #pragma unroll
      for (int f = 0; f < 2; ++f) {
        #pragma unroll
        for (int i = 0; i < 4; ++i) {
          const float v = fmaf(sc2.x, acc[f][c][i], sc2.y);
          INS5(tv[f * 4 + i], ti[f * 4 + i], v, node);
        }
        acc[f][c] = (f32x4)0.f;
      }
    }
    __syncthreads();
  }

  #pragma unroll
  for (int m = 1; m <= 8; m <<= 1) {
    #pragma unroll
    for (int r = 0; r < 8; ++r) {
      float ov[5]; int oi[5];
      #pragma unroll
      for (int q = 0; q < 5; ++q) {
        ov[q] = __shfl_xor(tv[r][q], m);
        oi[q] = __shfl_xor(ti[r][q], m);
      }
      #pragma unroll
      for (int q = 0; q < 5; ++q) INS5L(tv[r], ti[r], ov[q], oi[q]);
    }
  }
  if (ln15 == 0) {
    #pragma unroll
    for (int f = 0; f < 2; ++f)
      #pragma unroll
      for (int i = 0; i < 4; ++i) {
        const int row = 32 * wr + 16 * f + 4 * g + i;
        #pragma unroll
        for (int q = 0; q < 5; ++q) {
          mgv[row][wc][q] = tv[f * 4 + i][q];
          mgi[row][wc][q] = ti[f * 4 + i][q];
        }
      }
  }
  __syncthreads();
  if (tid < RT) {
    float mv[5]; int mi[5];
    #pragma unroll
    for (int q = 0; q < 5; ++q) { mv[q] = mgv[tid][0][q]; mi[q] = mgi[tid][0][q]; }
    #pragma unroll
    for (int q = 0; q < 5; ++q) INS5L(mv, mi, mgv[tid][1][q], mgi[tid][1][q]);
    const size_t o = ((size_t)(rowBase + tid) * NCH16 + blockIdx.y) * Kk;
    #pragma unroll
    for (int q = 0; q < 5; ++q) { candV[o + q] = mv[q]; candI[o + q] = mi[q]; }
  }
}

// ---------------------------------------------------------------------------
// Kernel 4 (shared): wave-per-row final merge -> gather-mean -> mobius_add.
__global__ __launch_bounds__(256) void k_fuse(
    const float* __restrict__ emb, const float* __restrict__ candV,
    const int* __restrict__ candI, const float* __restrict__ zhyp,
    float* __restrict__ out, int ncand)
{
  const int wv = threadIdx.x >> 6, ln = threadIdx.x & 63;
  const int row = blockIdx.x * 4 + wv;

  float mv[5]; int mi[5];
  #pragma unroll
  for (int q = 0; q < 5; ++q) { mv[q] = 3.0e38f; mi[q] = 0x7fffffff; }
  const size_t base = (size_t)row * ncand;
  for (int j = ln; j < ncand; j += 64) INS5L(mv, mi, candV[base + j], candI[base + j]);
  #pragma unroll
  for (int m = 1; m <= 32; m <<= 1) {
    float ov[5]; int oi[5];
    #pragma unroll
    for (int q = 0; q < 5; ++q) { ov[q] = __shfl_xor(mv[q], m); oi[q] = __shfl_xor(mi[q], m); }
    #pragma unroll
    for (int q = 0; q < 5; ++q) INS5L(mv, mi, ov[q], oi[q]);
  }
  // all lanes now hold the identical global top-5 indices
  float y0 = 0.f, y1 = 0.f;
  #pragma unroll
  for (int q = 0; q < Kk; ++q) {
    const float* e = emb + (size_t)mi[q] * Dd;
    y0 += e[ln]; y1 += e[ln + 64];
  }
  y0 *= 0.2f; y1 *= 0.2f;
  const float x0 = zhyp[(size_t)row * Dd + ln];
  const float x1 = zhyp[(size_t)row * Dd + ln + 64];
  float x2 = x0 * x0 + x1 * x1;
  float y2 = y0 * y0 + y1 * y1;
  float xy = x0 * y0 + x1 * y1;
  #pragma unroll
  for (int off = 32; off > 0; off >>= 1) {
    x2 += __shfl_xor(x2, off);
    y2 += __shfl_xor(y2, off);
    xy += __shfl_xor(xy, off);
  }
  const float ca = 1.f + 2.f * xy + y2;
  const float cb2 = 1.f - x2;
  const float den = 1.f / (1.f + 2.f * xy + x2 * y2 + EPSF);
  out[(size_t)row * Dd + ln] = (ca * x0 + cb2 * y0) * den;
  out[(size_t)row * Dd + ln + 64] = (ca * x1 + cb2 * y1) * den;
}

// ---------------------------------------------------------------------------
extern "C" void kernel_launch(void* const* d_in, const int* in_sizes, int n_in,
                              void* d_out, int out_size, void* d_ws, size_t ws_size,
                              hipStream_t stream)
{
  (void)in_sizes; (void)n_in; (void)out_size;
  const float* zseq = (const float*)d_in[0];
  const float* emb  = (const float*)d_in[1];
  const float* W    = (const float*)d_in[2];
  const float* bias = (const float*)d_in[3];
  float* out = (float*)d_out;            // [z_fused (B*D) | z_hyp (B*D)] f32

  const size_t ztbBytes   = (size_t)Bb * Dd * 2;                  // 524288
  const size_t embswBytes = (size_t)NCH8 * TIL8 * TILE_BYTES;     // 25690112
  const size_t cpadBytes  = (size_t)NCH8 * PAD8 * 4;              // 401408
  const size_t candVBytes = (size_t)Bb * NCH8 * Kk * 4;           // 327680
  const size_t needFast = ztbBytes + embswBytes + cpadBytes + 2 * candVBytes;

  if (ws_size >= needFast) {
    char* ws = (char*)d_ws;
    ushort* ztb   = (ushort*)ws;
    ushort* embsw = (ushort*)(ws + ztbBytes);
    float*  cpad  = (float*)(ws + ztbBytes + embswBytes);
    float*  candV = (float*)(ws + ztbBytes + embswBytes + cpadBytes);
    int*    candI = (int*)(ws + ztbBytes + embswBytes + cpadBytes + candVBytes);

    hipLaunchKernelGGL(k_prep, dim3(Bb / 8 + NCH8 * PAD8 / 8), dim3(256), 0,
                       stream, zseq, W, bias, out + HALF, ztb, emb, embsw, cpad);
    hipLaunchKernelGGL(k_topk8, dim3(256), dim3(1024), 0, stream,
                       ztb, embsw, cpad, candV, candI);
    hipLaunchKernelGGL(k_fuse, dim3(Bb / 4), dim3(256), 0, stream,
                       emb, candV, candI, out + HALF, out, NCH8 * Kk);
  } else {
    char* ws = (char*)d_ws;
    ushort* ztb  = (ushort*)ws;
    float* sArr  = (float*)(ws + ztbBytes);
    float* cArr  = sArr + Nn;
    float* candV = cArr + Nn;
    int*   candI = (int*)(candV + (size_t)Bb * NCH16 * Kk);

    hipLaunchKernelGGL(k_proj, dim3(Bb / 8), dim3(256), 0, stream,
                       zseq, W, bias, out + HALF, ztb);
    hipLaunchKernelGGL(k_node, dim3(Nn / 4), dim3(256), 0, stream, emb, sArr, cArr);
    hipLaunchKernelGGL(k_topk16, dim3(Bb / RT, NCH16), dim3(512), 0, stream,
                       ztb, emb, sArr, cArr, candV, candI);
    hipLaunchKernelGGL(k_fuse, dim3(Bb / 4), dim3(256), 0, stream,
                       emb, candV, candI, out + HALF, out, NCH16 * Kk);
  }
}